// Round 1
// baseline (460.116 us; speedup 1.0000x reference)
//
#include <hip/hip_runtime.h>
#include <hip/hip_bf16.h>
#include <math.h>

#define N_NODES 50000
#define E_EDGES 800000
#define IN_CH 128
#define HIDX 128   // HEADS*HID
#define OUT_CH 40
#define NEG_SLOPE 0.2f

// ---------------- CSR build ----------------

__global__ void zero_kernel(int* __restrict__ p, int n) {
    int i = blockIdx.x * blockDim.x + threadIdx.x;
    if (i < n) p[i] = 0;
}

__global__ void hist_kernel(const int* __restrict__ ei, int* __restrict__ deg) {
    int i = blockIdx.x * blockDim.x + threadIdx.x;
    if (i < E_EDGES) atomicAdd(&deg[ei[E_EDGES + i]], 1);
}

__global__ __launch_bounds__(1024) void scan_kernel(const int* __restrict__ deg,
                                                    int* __restrict__ rowptr,
                                                    int* __restrict__ cursor) {
    __shared__ int wsum[16];
    __shared__ int woff[16];
    int tid = threadIdx.x;
    int lane = tid & 63, wid = tid >> 6;
    int base = 0;
    for (int start = 0; start < N_NODES; start += 1024) {
        int i = start + tid;
        int v = (i < N_NODES) ? deg[i] : 0;
        int orig = v;
#pragma unroll
        for (int off = 1; off < 64; off <<= 1) {
            int t = __shfl_up(v, off);
            if (lane >= off) v += t;
        }
        if (lane == 63) wsum[wid] = v;
        __syncthreads();
        if (wid == 0) {
            int wv = (lane < 16) ? wsum[lane] : 0;
#pragma unroll
            for (int off = 1; off < 16; off <<= 1) {
                int t = __shfl_up(wv, off);
                if (lane >= off) wv += t;
            }
            if (lane < 16) woff[lane] = wv;
        }
        __syncthreads();
        int wbase = (wid == 0) ? 0 : woff[wid - 1];
        int excl = base + wbase + v - orig;
        if (i < N_NODES) { rowptr[i] = excl; cursor[i] = excl; }
        base += woff[15];
        __syncthreads();
    }
    if (tid == 0) rowptr[N_NODES] = E_EDGES;
}

__global__ void scatter_kernel(const int* __restrict__ ei, int* __restrict__ cursor,
                               int* __restrict__ csr_src) {
    int i = blockIdx.x * blockDim.x + threadIdx.x;
    if (i < E_EDGES) {
        int d = ei[E_EDGES + i];
        int pos = atomicAdd(&cursor[d], 1);
        csr_src[pos] = ei[i];
    }
}

// ---------------- Layer 1 GEMM: H1 = x @ W1, plus a_src/a_dst dots ----------------
// 64 rows/block, 256 threads; thread tile 4 rows x 8 cols. W1 (64KB) + x tile in LDS.

__global__ __launch_bounds__(256) void gemm1_kernel(
    const float* __restrict__ x, const float* __restrict__ W1,
    const float* __restrict__ as1, const float* __restrict__ ad1,
    float* __restrict__ H1, float* __restrict__ A1s, float* __restrict__ A1d)
{
    __shared__ float Ws[128 * 128];
    __shared__ float XT[64 * 132];
    int tid = threadIdx.x;
    int rowbase = blockIdx.x * 64;

    const float4* W4 = (const float4*)W1;
    float4* Ws4 = (float4*)Ws;
#pragma unroll
    for (int i = 0; i < 16; i++) Ws4[i * 256 + tid] = W4[i * 256 + tid];

    const float4* x4 = (const float4*)x;
#pragma unroll
    for (int i = 0; i < 8; i++) {
        int f = i * 256 + tid;
        int r = f >> 5, c4 = f & 31;
        int gr = rowbase + r; if (gr >= N_NODES) gr = N_NODES - 1;
        *(float4*)(XT + r * 132 + c4 * 4) = x4[gr * 32 + c4];
    }
    __syncthreads();

    int cg = tid & 15;   // col group of 8
    int rg = tid >> 4;   // row group of 4
    int c0 = cg * 8;
    int r0 = rg * 4;
    float acc[4][8];
#pragma unroll
    for (int i = 0; i < 4; i++)
#pragma unroll
        for (int j = 0; j < 8; j++) acc[i][j] = 0.f;

    for (int k = 0; k < 128; k++) {
        float xv[4];
#pragma unroll
        for (int i = 0; i < 4; i++) xv[i] = XT[(r0 + i) * 132 + k];
        float wv[8];
#pragma unroll
        for (int j = 0; j < 8; j++) wv[j] = Ws[k * 128 + c0 + j];
#pragma unroll
        for (int i = 0; i < 4; i++)
#pragma unroll
            for (int j = 0; j < 8; j++) acc[i][j] += xv[i] * wv[j];
    }

    // attention partial dots: cols c0..c0+7 lie in one head (c0 % 8 == 0, 16 ch/head)
    int hh = c0 >> 4;
    float asp[4] = {0, 0, 0, 0}, adp[4] = {0, 0, 0, 0};
#pragma unroll
    for (int j = 0; j < 8; j++) {
        float va = as1[c0 + j];
        float vd = ad1[c0 + j];
#pragma unroll
        for (int i = 0; i < 4; i++) { asp[i] += acc[i][j] * va; adp[i] += acc[i][j] * vd; }
    }
#pragma unroll
    for (int i = 0; i < 4; i++) {
        asp[i] += __shfl_xor(asp[i], 1);
        adp[i] += __shfl_xor(adp[i], 1);
    }
#pragma unroll
    for (int i = 0; i < 4; i++) {
        int gr = rowbase + r0 + i;
        if (gr < N_NODES) {
            float4 v0 = {acc[i][0], acc[i][1], acc[i][2], acc[i][3]};
            float4 v1 = {acc[i][4], acc[i][5], acc[i][6], acc[i][7]};
            *(float4*)(H1 + gr * 128 + c0) = v0;
            *(float4*)(H1 + gr * 128 + c0 + 4) = v1;
            if ((cg & 1) == 0) {
                A1s[gr * 8 + hh] = asp[i];
                A1d[gr * 8 + hh] = adp[i];
            }
        }
    }
}

// ---------------- Layer 1 aggregation: wave per node, softmax+gather fused ----------------

__global__ __launch_bounds__(256) void agg1_kernel(
    const int* __restrict__ rowptr, const int* __restrict__ csr_src,
    const float* __restrict__ A1s, const float* __restrict__ A1d,
    const float* __restrict__ H1, const float* __restrict__ b1,
    float* __restrict__ X2)
{
    int gwave = (blockIdx.x * blockDim.x + threadIdx.x) >> 6;
    int lane = threadIdx.x & 63;
    if (gwave >= N_NODES) return;
    int node = gwave;
    int beg = rowptr[node], end = rowptr[node + 1];
    int head = lane >> 3;        // col = 2*lane, head = col/16
    int col = lane * 2;
    float ad = A1d[node * 8 + head];
    float acc0 = 0.f, acc1 = 0.f, sumw = 0.f;
    for (int p = beg; p < end; ++p) {
        int s = csr_src[p];
        float z = A1s[s * 8 + head] + ad;
        z = z >= 0.f ? z : NEG_SLOPE * z;
        float w = expf(z);
        float2 hv = *(const float2*)(H1 + s * 128 + col);
        acc0 += w * hv.x;
        acc1 += w * hv.y;
        sumw += w;
    }
    float inv = (end > beg) ? 1.0f / sumw : 0.0f;
    float o0 = acc0 * inv + b1[col];
    float o1 = acc1 * inv + b1[col + 1];
    o0 = o0 > 0.f ? o0 : expm1f(o0);   // ELU
    o1 = o1 > 0.f ? o1 : expm1f(o1);
    float2 ov = {o0, o1};
    *(float2*)(X2 + node * 128 + col) = ov;
}

// ---------------- Layer 2 GEMM: H2 = X2 @ W2 (128->40) + attention dots ----------------
// 64 rows/block, 256 threads; 4 threads/row x 10 cols each.

__global__ __launch_bounds__(256) void gemm2_kernel(
    const float* __restrict__ X2, const float* __restrict__ W2,
    const float* __restrict__ as2, const float* __restrict__ ad2,
    float* __restrict__ H2, float* __restrict__ A2s, float* __restrict__ A2d)
{
    __shared__ float Ws[128 * 40];
    __shared__ float XS[64 * 132];
    int tid = threadIdx.x;
    int rowbase = blockIdx.x * 64;

#pragma unroll
    for (int i = 0; i < 20; i++) Ws[i * 256 + tid] = W2[i * 256 + tid];

    const float4* x4 = (const float4*)X2;
#pragma unroll
    for (int i = 0; i < 8; i++) {
        int f = i * 256 + tid;
        int r = f >> 5, c4 = f & 31;
        int gr = rowbase + r; if (gr >= N_NODES) gr = N_NODES - 1;
        *(float4*)(XS + r * 132 + c4 * 4) = x4[gr * 32 + c4];
    }
    __syncthreads();

    int q = tid & 3, r = tid >> 2;
    float acc[10];
#pragma unroll
    for (int j = 0; j < 10; j++) acc[j] = 0.f;
    for (int k = 0; k < 128; k++) {
        float xv = XS[r * 132 + k];
#pragma unroll
        for (int j = 0; j < 10; j++) acc[j] += xv * Ws[k * 40 + q * 10 + j];
    }
    float asum = 0.f, dsum = 0.f;
#pragma unroll
    for (int j = 0; j < 10; j++) {
        asum += acc[j] * as2[q * 10 + j];
        dsum += acc[j] * ad2[q * 10 + j];
    }
    asum += __shfl_xor(asum, 1); asum += __shfl_xor(asum, 2);
    dsum += __shfl_xor(dsum, 1); dsum += __shfl_xor(dsum, 2);
    int gr = rowbase + r;
    if (gr < N_NODES) {
#pragma unroll
        for (int j = 0; j < 10; j++) H2[gr * 40 + q * 10 + j] = acc[j];
        if (q == 0) { A2s[gr] = asum; A2d[gr] = dsum; }
    }
}

// ---------------- Layer 2 aggregation: wave per node ----------------

__global__ __launch_bounds__(256) void agg2_kernel(
    const int* __restrict__ rowptr, const int* __restrict__ csr_src,
    const float* __restrict__ A2s, const float* __restrict__ A2d,
    const float* __restrict__ H2, const float* __restrict__ b2,
    float* __restrict__ out)
{
    int gwave = (blockIdx.x * blockDim.x + threadIdx.x) >> 6;
    int lane = threadIdx.x & 63;
    if (gwave >= N_NODES) return;
    int node = gwave;
    int beg = rowptr[node], end = rowptr[node + 1];
    float ad = A2d[node];
    float acc = 0.f, sumw = 0.f;
    bool act = lane < OUT_CH;
    for (int p = beg; p < end; ++p) {
        int s = csr_src[p];
        float z = A2s[s] + ad;
        z = z >= 0.f ? z : NEG_SLOPE * z;
        float w = expf(z);
        float hv = act ? H2[s * OUT_CH + lane] : 0.f;
        acc += w * hv;
        sumw += w;
    }
    if (act) {
        float inv = (end > beg) ? 1.0f / sumw : 0.0f;
        out[node * OUT_CH + lane] = acc * inv + b2[lane];
    }
}

// ---------------- launch ----------------

extern "C" void kernel_launch(void* const* d_in, const int* in_sizes, int n_in,
                              void* d_out, int out_size, void* d_ws, size_t ws_size,
                              hipStream_t stream) {
    const float* x   = (const float*)d_in[0];
    const int*   ei  = (const int*)d_in[1];
    const float* W1  = (const float*)d_in[2];
    const float* as1 = (const float*)d_in[3];
    const float* ad1 = (const float*)d_in[4];
    const float* b1  = (const float*)d_in[5];
    const float* W2  = (const float*)d_in[6];
    const float* as2 = (const float*)d_in[7];
    const float* ad2 = (const float*)d_in[8];
    const float* b2  = (const float*)d_in[9];
    float* out = (float*)d_out;

    char* ws = (char*)d_ws;
    size_t off = 0;
    auto alloc = [&](size_t bytes) {
        void* p = ws + off;
        off += (bytes + 255) & ~size_t(255);
        return p;
    };
    float* H1     = (float*)alloc((size_t)N_NODES * 128 * 4);
    float* X2     = (float*)alloc((size_t)N_NODES * 128 * 4);
    float* H2     = (float*)alloc((size_t)N_NODES * OUT_CH * 4);
    float* A1s    = (float*)alloc((size_t)N_NODES * 8 * 4);
    float* A1d    = (float*)alloc((size_t)N_NODES * 8 * 4);
    float* A2s    = (float*)alloc((size_t)N_NODES * 4);
    float* A2d    = (float*)alloc((size_t)N_NODES * 4);
    int* deg      = (int*)alloc((size_t)N_NODES * 4);
    int* rowptr   = (int*)alloc((size_t)(N_NODES + 1) * 4);
    int* cursor   = (int*)alloc((size_t)N_NODES * 4);
    int* csr_src  = (int*)alloc((size_t)E_EDGES * 4);

    // CSR build
    zero_kernel<<<(N_NODES + 255) / 256, 256, 0, stream>>>(deg, N_NODES);
    hist_kernel<<<(E_EDGES + 255) / 256, 256, 0, stream>>>(ei, deg);
    scan_kernel<<<1, 1024, 0, stream>>>(deg, rowptr, cursor);
    scatter_kernel<<<(E_EDGES + 255) / 256, 256, 0, stream>>>(ei, cursor, csr_src);

    // Layer 1
    gemm1_kernel<<<(N_NODES + 63) / 64, 256, 0, stream>>>(x, W1, as1, ad1, H1, A1s, A1d);
    agg1_kernel<<<(N_NODES + 3) / 4, 256, 0, stream>>>(rowptr, csr_src, A1s, A1d, H1, b1, X2);

    // Layer 2
    gemm2_kernel<<<(N_NODES + 63) / 64, 256, 0, stream>>>(X2, W2, as2, ad2, H2, A2s, A2d);
    agg2_kernel<<<(N_NODES + 3) / 4, 256, 0, stream>>>(rowptr, csr_src, A2s, A2d, H2, b2, out);
}

// Round 2
// 341.371 us; speedup vs baseline: 1.3478x; 1.3478x over previous
//
#include <hip/hip_runtime.h>
#include <hip/hip_bf16.h>
#include <math.h>

#define N_NODES 50000
#define E_EDGES 800000
#define IN_CH 128
#define HIDX 128   // HEADS*HID
#define OUT_CH 40
#define NEG_SLOPE 0.2f
#define SCAN_NBLK ((N_NODES + 1023) / 1024)   // 49

// ---------------- CSR build ----------------

__global__ void zero_kernel(int* __restrict__ p, int n) {
    int i = blockIdx.x * blockDim.x + threadIdx.x;
    if (i < n) p[i] = 0;
}

__global__ void hist_kernel(const int* __restrict__ ei, int* __restrict__ deg) {
    int i = blockIdx.x * blockDim.x + threadIdx.x;
    if (i < E_EDGES) atomicAdd(&deg[ei[E_EDGES + i]], 1);
}

// pass 1: per-block exclusive scan into rowptr (block-local), block totals into bsum
__global__ __launch_bounds__(1024) void scan1_kernel(const int* __restrict__ deg,
                                                     int* __restrict__ rowptr,
                                                     int* __restrict__ bsum) {
    __shared__ int wsum[16];
    __shared__ int woff[16];
    int tid = threadIdx.x;
    int lane = tid & 63, wid = tid >> 6;
    int i = blockIdx.x * 1024 + tid;
    int v = (i < N_NODES) ? deg[i] : 0;
    int orig = v;
#pragma unroll
    for (int off = 1; off < 64; off <<= 1) {
        int t = __shfl_up(v, off);
        if (lane >= off) v += t;
    }
    if (lane == 63) wsum[wid] = v;
    __syncthreads();
    if (wid == 0) {
        int wv = (lane < 16) ? wsum[lane] : 0;
#pragma unroll
        for (int off = 1; off < 16; off <<= 1) {
            int t = __shfl_up(wv, off);
            if (lane >= off) wv += t;
        }
        if (lane < 16) woff[lane] = wv;
    }
    __syncthreads();
    int wbase = (wid == 0) ? 0 : woff[wid - 1];
    if (i < N_NODES) rowptr[i] = wbase + v - orig;
    if (tid == 0) bsum[blockIdx.x] = woff[15];
}

// pass 2: exclusive scan of the 49 block totals (one small block)
__global__ void scan2_kernel(int* __restrict__ bsum) {
    int lane = threadIdx.x;
    int v = (lane < SCAN_NBLK) ? bsum[lane] : 0;
    int orig = v;
#pragma unroll
    for (int off = 1; off < 64; off <<= 1) {
        int t = __shfl_up(v, off);
        if (lane >= off) v += t;
    }
    if (lane < SCAN_NBLK) bsum[lane] = v - orig;
}

// pass 3: add block offsets; produce final rowptr + cursor
__global__ __launch_bounds__(1024) void scan3_kernel(int* __restrict__ rowptr,
                                                     const int* __restrict__ bsum,
                                                     int* __restrict__ cursor) {
    int i = blockIdx.x * 1024 + threadIdx.x;
    if (i < N_NODES) {
        int v = rowptr[i] + bsum[blockIdx.x];
        rowptr[i] = v;
        cursor[i] = v;
    }
    if (i == 0) rowptr[N_NODES] = E_EDGES;
}

__global__ void scatter_kernel(const int* __restrict__ ei, int* __restrict__ cursor,
                               int* __restrict__ csr_src) {
    int i = blockIdx.x * blockDim.x + threadIdx.x;
    if (i < E_EDGES) {
        int d = ei[E_EDGES + i];
        int pos = atomicAdd(&cursor[d], 1);
        csr_src[pos] = ei[i];
    }
}

// ---------------- Layer 1 GEMM: H1 = x @ W1, plus a_src/a_dst dots ----------------
// 64 rows/block, 256 threads; thread tile 4 rows x 8 cols. W1 (64KB) + x tile in LDS.
// Inner loop k-unrolled x4 with ds_read_b128 on both operands.

__global__ __launch_bounds__(256) void gemm1_kernel(
    const float* __restrict__ x, const float* __restrict__ W1,
    const float* __restrict__ as1, const float* __restrict__ ad1,
    float* __restrict__ H1, float* __restrict__ A1s, float* __restrict__ A1d)
{
    __shared__ float Ws[128 * 128];
    __shared__ float XT[64 * 132];
    int tid = threadIdx.x;
    int rowbase = blockIdx.x * 64;

    const float4* W4 = (const float4*)W1;
    float4* Ws4 = (float4*)Ws;
#pragma unroll
    for (int i = 0; i < 16; i++) Ws4[i * 256 + tid] = W4[i * 256 + tid];

    const float4* x4 = (const float4*)x;
#pragma unroll
    for (int i = 0; i < 8; i++) {
        int f = i * 256 + tid;
        int r = f >> 5, c4 = f & 31;
        int gr = rowbase + r; if (gr >= N_NODES) gr = N_NODES - 1;
        *(float4*)(XT + r * 132 + c4 * 4) = x4[gr * 32 + c4];
    }
    __syncthreads();

    int cg = tid & 15;   // col group of 8
    int rg = tid >> 4;   // row group of 4
    int c0 = cg * 8;
    int r0 = rg * 4;
    float acc[4][8];
#pragma unroll
    for (int i = 0; i < 4; i++)
#pragma unroll
        for (int j = 0; j < 8; j++) acc[i][j] = 0.f;

    for (int k = 0; k < 128; k += 4) {
        float4 xv[4];
#pragma unroll
        for (int i = 0; i < 4; i++) xv[i] = *(const float4*)(XT + (r0 + i) * 132 + k);
#pragma unroll
        for (int kk = 0; kk < 4; kk++) {
            float4 wa = *(const float4*)(Ws + (k + kk) * 128 + c0);
            float4 wb = *(const float4*)(Ws + (k + kk) * 128 + c0 + 4);
#pragma unroll
            for (int i = 0; i < 4; i++) {
                float xs = (kk == 0) ? xv[i].x : (kk == 1) ? xv[i].y : (kk == 2) ? xv[i].z : xv[i].w;
                acc[i][0] += xs * wa.x; acc[i][1] += xs * wa.y;
                acc[i][2] += xs * wa.z; acc[i][3] += xs * wa.w;
                acc[i][4] += xs * wb.x; acc[i][5] += xs * wb.y;
                acc[i][6] += xs * wb.z; acc[i][7] += xs * wb.w;
            }
        }
    }

    // attention partial dots: cols c0..c0+7 lie in one head (c0 % 8 == 0, 16 ch/head)
    int hh = c0 >> 4;
    float asp[4] = {0, 0, 0, 0}, adp[4] = {0, 0, 0, 0};
#pragma unroll
    for (int j = 0; j < 8; j++) {
        float va = as1[c0 + j];
        float vd = ad1[c0 + j];
#pragma unroll
        for (int i = 0; i < 4; i++) { asp[i] += acc[i][j] * va; adp[i] += acc[i][j] * vd; }
    }
#pragma unroll
    for (int i = 0; i < 4; i++) {
        asp[i] += __shfl_xor(asp[i], 1);
        adp[i] += __shfl_xor(adp[i], 1);
    }
#pragma unroll
    for (int i = 0; i < 4; i++) {
        int gr = rowbase + r0 + i;
        if (gr < N_NODES) {
            float4 v0 = {acc[i][0], acc[i][1], acc[i][2], acc[i][3]};
            float4 v1 = {acc[i][4], acc[i][5], acc[i][6], acc[i][7]};
            *(float4*)(H1 + gr * 128 + c0) = v0;
            *(float4*)(H1 + gr * 128 + c0 + 4) = v1;
            if ((cg & 1) == 0) {
                A1s[gr * 8 + hh] = asp[i];
                A1d[gr * 8 + hh] = adp[i];
            }
        }
    }
}

// ---------------- Layer 1 aggregation: wave per node, softmax+gather fused ----------------
// Edge loop unrolled x4: 4 independent index->logit->row chains in flight.

__global__ __launch_bounds__(256) void agg1_kernel(
    const int* __restrict__ rowptr, const int* __restrict__ csr_src,
    const float* __restrict__ A1s, const float* __restrict__ A1d,
    const float* __restrict__ H1, const float* __restrict__ b1,
    float* __restrict__ X2)
{
    int gwave = (blockIdx.x * blockDim.x + threadIdx.x) >> 6;
    int lane = threadIdx.x & 63;
    if (gwave >= N_NODES) return;
    int node = gwave;
    int beg = rowptr[node], end = rowptr[node + 1];
    int head = lane >> 3;        // col = 2*lane, head = col/16
    int col = lane * 2;
    float ad = A1d[node * 8 + head];
    float acc0 = 0.f, acc1 = 0.f, sumw = 0.f;
    int p = beg;
    for (; p + 4 <= end; p += 4) {
        int s0 = csr_src[p + 0];
        int s1 = csr_src[p + 1];
        int s2 = csr_src[p + 2];
        int s3 = csr_src[p + 3];
        float a0 = A1s[s0 * 8 + head];
        float a1 = A1s[s1 * 8 + head];
        float a2 = A1s[s2 * 8 + head];
        float a3 = A1s[s3 * 8 + head];
        float2 h0 = *(const float2*)(H1 + s0 * 128 + col);
        float2 h1 = *(const float2*)(H1 + s1 * 128 + col);
        float2 h2 = *(const float2*)(H1 + s2 * 128 + col);
        float2 h3 = *(const float2*)(H1 + s3 * 128 + col);
        float z0 = a0 + ad; z0 = z0 >= 0.f ? z0 : NEG_SLOPE * z0; float w0 = __expf(z0);
        float z1 = a1 + ad; z1 = z1 >= 0.f ? z1 : NEG_SLOPE * z1; float w1 = __expf(z1);
        float z2 = a2 + ad; z2 = z2 >= 0.f ? z2 : NEG_SLOPE * z2; float w2 = __expf(z2);
        float z3 = a3 + ad; z3 = z3 >= 0.f ? z3 : NEG_SLOPE * z3; float w3 = __expf(z3);
        acc0 += w0 * h0.x + w1 * h1.x + w2 * h2.x + w3 * h3.x;
        acc1 += w0 * h0.y + w1 * h1.y + w2 * h2.y + w3 * h3.y;
        sumw += w0 + w1 + w2 + w3;
    }
    for (; p < end; ++p) {
        int s = csr_src[p];
        float z = A1s[s * 8 + head] + ad;
        z = z >= 0.f ? z : NEG_SLOPE * z;
        float w = __expf(z);
        float2 hv = *(const float2*)(H1 + s * 128 + col);
        acc0 += w * hv.x;
        acc1 += w * hv.y;
        sumw += w;
    }
    float inv = (end > beg) ? 1.0f / sumw : 0.0f;
    float o0 = acc0 * inv + b1[col];
    float o1 = acc1 * inv + b1[col + 1];
    o0 = o0 > 0.f ? o0 : expm1f(o0);   // ELU
    o1 = o1 > 0.f ? o1 : expm1f(o1);
    float2 ov = {o0, o1};
    *(float2*)(X2 + node * 128 + col) = ov;
}

// ---------------- Layer 2 GEMM: H2 = X2 @ W2 (128->40) + attention dots ----------------
// 64 rows/block, 256 threads; 4 threads/row x 10 cols each. k-unroll x4 via float4 XS reads.

__global__ __launch_bounds__(256) void gemm2_kernel(
    const float* __restrict__ X2, const float* __restrict__ W2,
    const float* __restrict__ as2, const float* __restrict__ ad2,
    float* __restrict__ H2, float* __restrict__ A2s, float* __restrict__ A2d)
{
    __shared__ float Ws[128 * 40];
    __shared__ float XS[64 * 132];
    int tid = threadIdx.x;
    int rowbase = blockIdx.x * 64;

#pragma unroll
    for (int i = 0; i < 20; i++) Ws[i * 256 + tid] = W2[i * 256 + tid];

    const float4* x4 = (const float4*)X2;
#pragma unroll
    for (int i = 0; i < 8; i++) {
        int f = i * 256 + tid;
        int r = f >> 5, c4 = f & 31;
        int gr = rowbase + r; if (gr >= N_NODES) gr = N_NODES - 1;
        *(float4*)(XS + r * 132 + c4 * 4) = x4[gr * 32 + c4];
    }
    __syncthreads();

    int q = tid & 3, r = tid >> 2;
    float acc[10];
#pragma unroll
    for (int j = 0; j < 10; j++) acc[j] = 0.f;
    for (int k = 0; k < 128; k += 4) {
        float4 xv = *(const float4*)(XS + r * 132 + k);
#pragma unroll
        for (int kk = 0; kk < 4; kk++) {
            float xs = (kk == 0) ? xv.x : (kk == 1) ? xv.y : (kk == 2) ? xv.z : xv.w;
#pragma unroll
            for (int j = 0; j < 10; j++) acc[j] += xs * Ws[(k + kk) * 40 + q * 10 + j];
        }
    }
    float asum = 0.f, dsum = 0.f;
#pragma unroll
    for (int j = 0; j < 10; j++) {
        asum += acc[j] * as2[q * 10 + j];
        dsum += acc[j] * ad2[q * 10 + j];
    }
    asum += __shfl_xor(asum, 1); asum += __shfl_xor(asum, 2);
    dsum += __shfl_xor(dsum, 1); dsum += __shfl_xor(dsum, 2);
    int gr = rowbase + r;
    if (gr < N_NODES) {
#pragma unroll
        for (int j = 0; j < 10; j++) H2[gr * 40 + q * 10 + j] = acc[j];
        if (q == 0) { A2s[gr] = asum; A2d[gr] = dsum; }
    }
}

// ---------------- Layer 2 aggregation: wave per node, edge loop unrolled x4 ----------------

__global__ __launch_bounds__(256) void agg2_kernel(
    const int* __restrict__ rowptr, const int* __restrict__ csr_src,
    const float* __restrict__ A2s, const float* __restrict__ A2d,
    const float* __restrict__ H2, const float* __restrict__ b2,
    float* __restrict__ out)
{
    int gwave = (blockIdx.x * blockDim.x + threadIdx.x) >> 6;
    int lane = threadIdx.x & 63;
    if (gwave >= N_NODES) return;
    int node = gwave;
    int beg = rowptr[node], end = rowptr[node + 1];
    float ad = A2d[node];
    float acc = 0.f, sumw = 0.f;
    bool act = lane < OUT_CH;
    int p = beg;
    for (; p + 4 <= end; p += 4) {
        int s0 = csr_src[p + 0];
        int s1 = csr_src[p + 1];
        int s2 = csr_src[p + 2];
        int s3 = csr_src[p + 3];
        float a0 = A2s[s0];
        float a1 = A2s[s1];
        float a2 = A2s[s2];
        float a3 = A2s[s3];
        float h0 = act ? H2[s0 * OUT_CH + lane] : 0.f;
        float h1 = act ? H2[s1 * OUT_CH + lane] : 0.f;
        float h2 = act ? H2[s2 * OUT_CH + lane] : 0.f;
        float h3 = act ? H2[s3 * OUT_CH + lane] : 0.f;
        float z0 = a0 + ad; z0 = z0 >= 0.f ? z0 : NEG_SLOPE * z0; float w0 = __expf(z0);
        float z1 = a1 + ad; z1 = z1 >= 0.f ? z1 : NEG_SLOPE * z1; float w1 = __expf(z1);
        float z2 = a2 + ad; z2 = z2 >= 0.f ? z2 : NEG_SLOPE * z2; float w2 = __expf(z2);
        float z3 = a3 + ad; z3 = z3 >= 0.f ? z3 : NEG_SLOPE * z3; float w3 = __expf(z3);
        acc += w0 * h0 + w1 * h1 + w2 * h2 + w3 * h3;
        sumw += w0 + w1 + w2 + w3;
    }
    for (; p < end; ++p) {
        int s = csr_src[p];
        float z = A2s[s] + ad;
        z = z >= 0.f ? z : NEG_SLOPE * z;
        float w = __expf(z);
        float hv = act ? H2[s * OUT_CH + lane] : 0.f;
        acc += w * hv;
        sumw += w;
    }
    if (act) {
        float inv = (end > beg) ? 1.0f / sumw : 0.0f;
        out[node * OUT_CH + lane] = acc * inv + b2[lane];
    }
}

// ---------------- launch ----------------

extern "C" void kernel_launch(void* const* d_in, const int* in_sizes, int n_in,
                              void* d_out, int out_size, void* d_ws, size_t ws_size,
                              hipStream_t stream) {
    const float* x   = (const float*)d_in[0];
    const int*   ei  = (const int*)d_in[1];
    const float* W1  = (const float*)d_in[2];
    const float* as1 = (const float*)d_in[3];
    const float* ad1 = (const float*)d_in[4];
    const float* b1  = (const float*)d_in[5];
    const float* W2  = (const float*)d_in[6];
    const float* as2 = (const float*)d_in[7];
    const float* ad2 = (const float*)d_in[8];
    const float* b2  = (const float*)d_in[9];
    float* out = (float*)d_out;

    char* ws = (char*)d_ws;
    size_t off = 0;
    auto alloc = [&](size_t bytes) {
        void* p = ws + off;
        off += (bytes + 255) & ~size_t(255);
        return p;
    };
    float* H1     = (float*)alloc((size_t)N_NODES * 128 * 4);
    float* X2     = (float*)alloc((size_t)N_NODES * 128 * 4);
    float* H2     = (float*)alloc((size_t)N_NODES * OUT_CH * 4);
    float* A1s    = (float*)alloc((size_t)N_NODES * 8 * 4);
    float* A1d    = (float*)alloc((size_t)N_NODES * 8 * 4);
    float* A2s    = (float*)alloc((size_t)N_NODES * 4);
    float* A2d    = (float*)alloc((size_t)N_NODES * 4);
    int* deg      = (int*)alloc((size_t)N_NODES * 4);
    int* rowptr   = (int*)alloc((size_t)(N_NODES + 1) * 4);
    int* cursor   = (int*)alloc((size_t)N_NODES * 4);
    int* csr_src  = (int*)alloc((size_t)E_EDGES * 4);
    int* bsum     = (int*)alloc((size_t)SCAN_NBLK * 4);

    // CSR build
    zero_kernel<<<(N_NODES + 255) / 256, 256, 0, stream>>>(deg, N_NODES);
    hist_kernel<<<(E_EDGES + 255) / 256, 256, 0, stream>>>(ei, deg);
    scan1_kernel<<<SCAN_NBLK, 1024, 0, stream>>>(deg, rowptr, bsum);
    scan2_kernel<<<1, 64, 0, stream>>>(bsum);
    scan3_kernel<<<SCAN_NBLK, 1024, 0, stream>>>(rowptr, bsum, cursor);
    scatter_kernel<<<(E_EDGES + 255) / 256, 256, 0, stream>>>(ei, cursor, csr_src);

    // Layer 1
    gemm1_kernel<<<(N_NODES + 63) / 64, 256, 0, stream>>>(x, W1, as1, ad1, H1, A1s, A1d);
    agg1_kernel<<<(N_NODES + 3) / 4, 256, 0, stream>>>(rowptr, csr_src, A1s, A1d, H1, b1, X2);

    // Layer 2
    gemm2_kernel<<<(N_NODES + 63) / 64, 256, 0, stream>>>(X2, W2, as2, ad2, H2, A2s, A2d);
    agg2_kernel<<<(N_NODES + 3) / 4, 256, 0, stream>>>(rowptr, csr_src, A2s, A2d, H2, b2, out);
}

// Round 3
// 328.527 us; speedup vs baseline: 1.4005x; 1.0391x over previous
//
#include <hip/hip_runtime.h>
#include <hip/hip_bf16.h>
#include <math.h>

#define N_NODES 50000
#define E_EDGES 800000
#define IN_CH 128
#define HIDX 128   // HEADS*HID
#define OUT_CH 40
#define NEG_SLOPE 0.2f
#define SCAN_NBLK ((N_NODES + 1023) / 1024)   // 49

// bf16 helpers (RNE)
static __device__ __forceinline__ unsigned int f2bf_pk(float lo, float hi) {
    unsigned int ul = __float_as_uint(lo);
    unsigned int uh = __float_as_uint(hi);
    ul = (ul + 0x7fffu + ((ul >> 16) & 1u)) >> 16;
    uh = (uh + 0x7fffu + ((uh >> 16) & 1u)) >> 16;
    return ul | (uh << 16);
}
static __device__ __forceinline__ float bf2f(unsigned short u) {
    return __uint_as_float(((unsigned int)u) << 16);
}

// ---------------- CSR build ----------------

__global__ void zero_kernel(int* __restrict__ p, int n) {
    int i = blockIdx.x * blockDim.x + threadIdx.x;
    if (i < n) p[i] = 0;
}

__global__ void hist_kernel(const int* __restrict__ ei, int* __restrict__ deg) {
    int i = blockIdx.x * blockDim.x + threadIdx.x;
    if (i < E_EDGES) atomicAdd(&deg[ei[E_EDGES + i]], 1);
}

__global__ __launch_bounds__(1024) void scan1_kernel(const int* __restrict__ deg,
                                                     int* __restrict__ rowptr,
                                                     int* __restrict__ bsum) {
    __shared__ int wsum[16];
    __shared__ int woff[16];
    int tid = threadIdx.x;
    int lane = tid & 63, wid = tid >> 6;
    int i = blockIdx.x * 1024 + tid;
    int v = (i < N_NODES) ? deg[i] : 0;
    int orig = v;
#pragma unroll
    for (int off = 1; off < 64; off <<= 1) {
        int t = __shfl_up(v, off);
        if (lane >= off) v += t;
    }
    if (lane == 63) wsum[wid] = v;
    __syncthreads();
    if (wid == 0) {
        int wv = (lane < 16) ? wsum[lane] : 0;
#pragma unroll
        for (int off = 1; off < 16; off <<= 1) {
            int t = __shfl_up(wv, off);
            if (lane >= off) wv += t;
        }
        if (lane < 16) woff[lane] = wv;
    }
    __syncthreads();
    int wbase = (wid == 0) ? 0 : woff[wid - 1];
    if (i < N_NODES) rowptr[i] = wbase + v - orig;
    if (tid == 0) bsum[blockIdx.x] = woff[15];
}

__global__ void scan2_kernel(int* __restrict__ bsum) {
    int lane = threadIdx.x;
    int v = (lane < SCAN_NBLK) ? bsum[lane] : 0;
    int orig = v;
#pragma unroll
    for (int off = 1; off < 64; off <<= 1) {
        int t = __shfl_up(v, off);
        if (lane >= off) v += t;
    }
    if (lane < SCAN_NBLK) bsum[lane] = v - orig;
}

__global__ __launch_bounds__(1024) void scan3_kernel(int* __restrict__ rowptr,
                                                     const int* __restrict__ bsum,
                                                     int* __restrict__ cursor) {
    int i = blockIdx.x * 1024 + threadIdx.x;
    if (i < N_NODES) {
        int v = rowptr[i] + bsum[blockIdx.x];
        rowptr[i] = v;
        cursor[i] = v;
    }
    if (i == 0) rowptr[N_NODES] = E_EDGES;
}

__global__ void scatter_kernel(const int* __restrict__ ei, int* __restrict__ cursor,
                               int* __restrict__ csr_src) {
    int i = blockIdx.x * blockDim.x + threadIdx.x;
    if (i < E_EDGES) {
        int d = ei[E_EDGES + i];
        int pos = atomicAdd(&cursor[d], 1);
        csr_src[pos] = ei[i];
    }
}

// ---------------- Layer 1 GEMM: H1(bf16) = x @ W1, plus a_src/a_dst dots (fp32) ----------------

__global__ __launch_bounds__(256) void gemm1_kernel(
    const float* __restrict__ x, const float* __restrict__ W1,
    const float* __restrict__ as1, const float* __restrict__ ad1,
    unsigned short* __restrict__ H1, float* __restrict__ A1s, float* __restrict__ A1d)
{
    __shared__ float Ws[128 * 128];
    __shared__ float XT[64 * 132];
    int tid = threadIdx.x;
    int rowbase = blockIdx.x * 64;

    const float4* W4 = (const float4*)W1;
    float4* Ws4 = (float4*)Ws;
#pragma unroll
    for (int i = 0; i < 16; i++) Ws4[i * 256 + tid] = W4[i * 256 + tid];

    const float4* x4 = (const float4*)x;
#pragma unroll
    for (int i = 0; i < 8; i++) {
        int f = i * 256 + tid;
        int r = f >> 5, c4 = f & 31;
        int gr = rowbase + r; if (gr >= N_NODES) gr = N_NODES - 1;
        *(float4*)(XT + r * 132 + c4 * 4) = x4[gr * 32 + c4];
    }
    __syncthreads();

    int cg = tid & 15;   // col group of 8
    int rg = tid >> 4;   // row group of 4
    int c0 = cg * 8;
    int r0 = rg * 4;
    float acc[4][8];
#pragma unroll
    for (int i = 0; i < 4; i++)
#pragma unroll
        for (int j = 0; j < 8; j++) acc[i][j] = 0.f;

    for (int k = 0; k < 128; k += 4) {
        float4 xv[4];
#pragma unroll
        for (int i = 0; i < 4; i++) xv[i] = *(const float4*)(XT + (r0 + i) * 132 + k);
#pragma unroll
        for (int kk = 0; kk < 4; kk++) {
            float4 wa = *(const float4*)(Ws + (k + kk) * 128 + c0);
            float4 wb = *(const float4*)(Ws + (k + kk) * 128 + c0 + 4);
#pragma unroll
            for (int i = 0; i < 4; i++) {
                float xs = (kk == 0) ? xv[i].x : (kk == 1) ? xv[i].y : (kk == 2) ? xv[i].z : xv[i].w;
                acc[i][0] += xs * wa.x; acc[i][1] += xs * wa.y;
                acc[i][2] += xs * wa.z; acc[i][3] += xs * wa.w;
                acc[i][4] += xs * wb.x; acc[i][5] += xs * wb.y;
                acc[i][6] += xs * wb.z; acc[i][7] += xs * wb.w;
            }
        }
    }

    int hh = c0 >> 4;
    float asp[4] = {0, 0, 0, 0}, adp[4] = {0, 0, 0, 0};
#pragma unroll
    for (int j = 0; j < 8; j++) {
        float va = as1[c0 + j];
        float vd = ad1[c0 + j];
#pragma unroll
        for (int i = 0; i < 4; i++) { asp[i] += acc[i][j] * va; adp[i] += acc[i][j] * vd; }
    }
#pragma unroll
    for (int i = 0; i < 4; i++) {
        asp[i] += __shfl_xor(asp[i], 1);
        adp[i] += __shfl_xor(adp[i], 1);
    }
#pragma unroll
    for (int i = 0; i < 4; i++) {
        int gr = rowbase + r0 + i;
        if (gr < N_NODES) {
            uint4 v;
            v.x = f2bf_pk(acc[i][0], acc[i][1]);
            v.y = f2bf_pk(acc[i][2], acc[i][3]);
            v.z = f2bf_pk(acc[i][4], acc[i][5]);
            v.w = f2bf_pk(acc[i][6], acc[i][7]);
            *(uint4*)(H1 + gr * 128 + c0) = v;
            if ((cg & 1) == 0) {
                A1s[gr * 8 + hh] = asp[i];
                A1d[gr * 8 + hh] = adp[i];
            }
        }
    }
}

// ---------------- Layer 1 aggregation: wave per node, 2 edges per wave (32-lane halves) ----------------
// half h handles edge p+h; lane-in-half li covers channels 4*li..4*li+3 (head = li>>2).
// H1 rows are bf16 (256B); ushort4 loads are fully coalesced per half.

__global__ __launch_bounds__(256) void agg1_kernel(
    const int* __restrict__ rowptr, const int* __restrict__ csr_src,
    const float* __restrict__ A1s, const float* __restrict__ A1d,
    const unsigned short* __restrict__ H1, const float* __restrict__ b1,
    float* __restrict__ X2)
{
    int gwave = (blockIdx.x * blockDim.x + threadIdx.x) >> 6;
    int lane = threadIdx.x & 63;
    if (gwave >= N_NODES) return;
    int node = gwave;
    int beg = rowptr[node], end = rowptr[node + 1];
    int half = lane >> 5;
    int li = lane & 31;
    int head = li >> 2;
    int c0 = li * 4;
    float ad = A1d[node * 8 + head];
    float acc0 = 0.f, acc1 = 0.f, acc2 = 0.f, acc3 = 0.f, sumw = 0.f;
    int p = beg;
    // 4 edges per iteration (2 per half) -> 2 independent chains per half
    for (; p + 4 <= end; p += 4) {
        int s0 = csr_src[p + half];
        int s1 = csr_src[p + 2 + half];
        float a0 = A1s[s0 * 8 + head];
        float a1 = A1s[s1 * 8 + head];
        ushort4 u0 = *(const ushort4*)(H1 + s0 * 128 + c0);
        ushort4 u1 = *(const ushort4*)(H1 + s1 * 128 + c0);
        float z0 = a0 + ad; z0 = z0 >= 0.f ? z0 : NEG_SLOPE * z0; float w0 = __expf(z0);
        float z1 = a1 + ad; z1 = z1 >= 0.f ? z1 : NEG_SLOPE * z1; float w1 = __expf(z1);
        acc0 += w0 * bf2f(u0.x) + w1 * bf2f(u1.x);
        acc1 += w0 * bf2f(u0.y) + w1 * bf2f(u1.y);
        acc2 += w0 * bf2f(u0.z) + w1 * bf2f(u1.z);
        acc3 += w0 * bf2f(u0.w) + w1 * bf2f(u1.w);
        sumw += w0 + w1;
    }
    for (; p < end; p += 2) {
        int e = p + half;
        bool valid = e < end;
        int s = csr_src[valid ? e : beg];
        float a = A1s[s * 8 + head];
        ushort4 u = *(const ushort4*)(H1 + s * 128 + c0);
        float z = a + ad; z = z >= 0.f ? z : NEG_SLOPE * z;
        float w = valid ? __expf(z) : 0.f;
        acc0 += w * bf2f(u.x);
        acc1 += w * bf2f(u.y);
        acc2 += w * bf2f(u.z);
        acc3 += w * bf2f(u.w);
        sumw += w;
    }
    // combine the two halves
    acc0 += __shfl_xor(acc0, 32);
    acc1 += __shfl_xor(acc1, 32);
    acc2 += __shfl_xor(acc2, 32);
    acc3 += __shfl_xor(acc3, 32);
    sumw += __shfl_xor(sumw, 32);
    if (half == 0) {
        float inv = (end > beg) ? 1.0f / sumw : 0.0f;
        float4 bv = *(const float4*)(b1 + c0);
        float o0 = acc0 * inv + bv.x;
        float o1 = acc1 * inv + bv.y;
        float o2 = acc2 * inv + bv.z;
        float o3 = acc3 * inv + bv.w;
        o0 = o0 > 0.f ? o0 : expm1f(o0);
        o1 = o1 > 0.f ? o1 : expm1f(o1);
        o2 = o2 > 0.f ? o2 : expm1f(o2);
        o3 = o3 > 0.f ? o3 : expm1f(o3);
        float4 ov = {o0, o1, o2, o3};
        *(float4*)(X2 + node * 128 + c0) = ov;
    }
}

// ---------------- Layer 2 GEMM: H2 = X2 @ W2 (128->40) + attention dots ----------------

__global__ __launch_bounds__(256) void gemm2_kernel(
    const float* __restrict__ X2, const float* __restrict__ W2,
    const float* __restrict__ as2, const float* __restrict__ ad2,
    float* __restrict__ H2, float* __restrict__ A2s, float* __restrict__ A2d)
{
    __shared__ float Ws[128 * 40];
    __shared__ float XS[64 * 132];
    int tid = threadIdx.x;
    int rowbase = blockIdx.x * 64;

#pragma unroll
    for (int i = 0; i < 20; i++) Ws[i * 256 + tid] = W2[i * 256 + tid];

    const float4* x4 = (const float4*)X2;
#pragma unroll
    for (int i = 0; i < 8; i++) {
        int f = i * 256 + tid;
        int r = f >> 5, c4 = f & 31;
        int gr = rowbase + r; if (gr >= N_NODES) gr = N_NODES - 1;
        *(float4*)(XS + r * 132 + c4 * 4) = x4[gr * 32 + c4];
    }
    __syncthreads();

    int q = tid & 3, r = tid >> 2;
    float acc[10];
#pragma unroll
    for (int j = 0; j < 10; j++) acc[j] = 0.f;
    for (int k = 0; k < 128; k += 4) {
        float4 xv = *(const float4*)(XS + r * 132 + k);
#pragma unroll
        for (int kk = 0; kk < 4; kk++) {
            float xs = (kk == 0) ? xv.x : (kk == 1) ? xv.y : (kk == 2) ? xv.z : xv.w;
#pragma unroll
            for (int j = 0; j < 10; j++) acc[j] += xs * Ws[(k + kk) * 40 + q * 10 + j];
        }
    }
    float asum = 0.f, dsum = 0.f;
#pragma unroll
    for (int j = 0; j < 10; j++) {
        asum += acc[j] * as2[q * 10 + j];
        dsum += acc[j] * ad2[q * 10 + j];
    }
    asum += __shfl_xor(asum, 1); asum += __shfl_xor(asum, 2);
    dsum += __shfl_xor(dsum, 1); dsum += __shfl_xor(dsum, 2);
    int gr = rowbase + r;
    if (gr < N_NODES) {
#pragma unroll
        for (int j = 0; j < 10; j++) H2[gr * 40 + q * 10 + j] = acc[j];
        if (q == 0) { A2s[gr] = asum; A2d[gr] = dsum; }
    }
}

// ---------------- Layer 2 aggregation: wave per node, edge loop unrolled x4 ----------------

__global__ __launch_bounds__(256) void agg2_kernel(
    const int* __restrict__ rowptr, const int* __restrict__ csr_src,
    const float* __restrict__ A2s, const float* __restrict__ A2d,
    const float* __restrict__ H2, const float* __restrict__ b2,
    float* __restrict__ out)
{
    int gwave = (blockIdx.x * blockDim.x + threadIdx.x) >> 6;
    int lane = threadIdx.x & 63;
    if (gwave >= N_NODES) return;
    int node = gwave;
    int beg = rowptr[node], end = rowptr[node + 1];
    float ad = A2d[node];
    float acc = 0.f, sumw = 0.f;
    bool act = lane < OUT_CH;
    int p = beg;
    for (; p + 4 <= end; p += 4) {
        int s0 = csr_src[p + 0];
        int s1 = csr_src[p + 1];
        int s2 = csr_src[p + 2];
        int s3 = csr_src[p + 3];
        float a0 = A2s[s0];
        float a1 = A2s[s1];
        float a2 = A2s[s2];
        float a3 = A2s[s3];
        float h0 = act ? H2[s0 * OUT_CH + lane] : 0.f;
        float h1 = act ? H2[s1 * OUT_CH + lane] : 0.f;
        float h2 = act ? H2[s2 * OUT_CH + lane] : 0.f;
        float h3 = act ? H2[s3 * OUT_CH + lane] : 0.f;
        float z0 = a0 + ad; z0 = z0 >= 0.f ? z0 : NEG_SLOPE * z0; float w0 = __expf(z0);
        float z1 = a1 + ad; z1 = z1 >= 0.f ? z1 : NEG_SLOPE * z1; float w1 = __expf(z1);
        float z2 = a2 + ad; z2 = z2 >= 0.f ? z2 : NEG_SLOPE * z2; float w2 = __expf(z2);
        float z3 = a3 + ad; z3 = z3 >= 0.f ? z3 : NEG_SLOPE * z3; float w3 = __expf(z3);
        acc += w0 * h0 + w1 * h1 + w2 * h2 + w3 * h3;
        sumw += w0 + w1 + w2 + w3;
    }
    for (; p < end; ++p) {
        int s = csr_src[p];
        float z = A2s[s] + ad;
        z = z >= 0.f ? z : NEG_SLOPE * z;
        float w = __expf(z);
        float hv = act ? H2[s * OUT_CH + lane] : 0.f;
        acc += w * hv;
        sumw += w;
    }
    if (act) {
        float inv = (end > beg) ? 1.0f / sumw : 0.0f;
        out[node * OUT_CH + lane] = acc * inv + b2[lane];
    }
}

// ---------------- launch ----------------

extern "C" void kernel_launch(void* const* d_in, const int* in_sizes, int n_in,
                              void* d_out, int out_size, void* d_ws, size_t ws_size,
                              hipStream_t stream) {
    const float* x   = (const float*)d_in[0];
    const int*   ei  = (const int*)d_in[1];
    const float* W1  = (const float*)d_in[2];
    const float* as1 = (const float*)d_in[3];
    const float* ad1 = (const float*)d_in[4];
    const float* b1  = (const float*)d_in[5];
    const float* W2  = (const float*)d_in[6];
    const float* as2 = (const float*)d_in[7];
    const float* ad2 = (const float*)d_in[8];
    const float* b2  = (const float*)d_in[9];
    float* out = (float*)d_out;

    char* ws = (char*)d_ws;
    size_t off = 0;
    auto alloc = [&](size_t bytes) {
        void* p = ws + off;
        off += (bytes + 255) & ~size_t(255);
        return p;
    };
    unsigned short* H1 = (unsigned short*)alloc((size_t)N_NODES * 128 * 2);
    float* X2     = (float*)alloc((size_t)N_NODES * 128 * 4);
    float* H2     = (float*)alloc((size_t)N_NODES * OUT_CH * 4);
    float* A1s    = (float*)alloc((size_t)N_NODES * 8 * 4);
    float* A1d    = (float*)alloc((size_t)N_NODES * 8 * 4);
    float* A2s    = (float*)alloc((size_t)N_NODES * 4);
    float* A2d    = (float*)alloc((size_t)N_NODES * 4);
    int* deg      = (int*)alloc((size_t)N_NODES * 4);
    int* rowptr   = (int*)alloc((size_t)(N_NODES + 1) * 4);
    int* cursor   = (int*)alloc((size_t)N_NODES * 4);
    int* csr_src  = (int*)alloc((size_t)E_EDGES * 4);
    int* bsum     = (int*)alloc((size_t)SCAN_NBLK * 4);

    // CSR build
    zero_kernel<<<(N_NODES + 255) / 256, 256, 0, stream>>>(deg, N_NODES);
    hist_kernel<<<(E_EDGES + 255) / 256, 256, 0, stream>>>(ei, deg);
    scan1_kernel<<<SCAN_NBLK, 1024, 0, stream>>>(deg, rowptr, bsum);
    scan2_kernel<<<1, 64, 0, stream>>>(bsum);
    scan3_kernel<<<SCAN_NBLK, 1024, 0, stream>>>(rowptr, bsum, cursor);
    scatter_kernel<<<(E_EDGES + 255) / 256, 256, 0, stream>>>(ei, cursor, csr_src);

    // Layer 1
    gemm1_kernel<<<(N_NODES + 63) / 64, 256, 0, stream>>>(x, W1, as1, ad1, H1, A1s, A1d);
    agg1_kernel<<<(N_NODES + 3) / 4, 256, 0, stream>>>(rowptr, csr_src, A1s, A1d, H1, b1, X2);

    // Layer 2
    gemm2_kernel<<<(N_NODES + 63) / 64, 256, 0, stream>>>(X2, W2, as2, ad2, H2, A2s, A2d);
    agg2_kernel<<<(N_NODES + 3) / 4, 256, 0, stream>>>(rowptr, csr_src, A2s, A2d, H2, b2, out);
}